// Round 5
// baseline (90.033 us; speedup 1.0000x reference)
//
#include <hip/hip_runtime.h>

// Quantum state-vector simulation: out[b] = Re( M[b>>2] @ input[b] ),
// M = prod over 8 layers of (ENTANGLE @ Rot(params)).
// Qubit q <-> bit (9-q) of amplitude index. Entangling CNOT chain applied to a
// vector == Gray-code index permutation: state'[x ^ (x>>1)] = state[x].
//
// R5 structure: ONE WAVE PER VECTOR, state in registers (16 amps/lane),
// zero __syncthreads in the main loop. Qubits 6-9 are register-local;
// qubits 0-5 use __shfl_xor lane exchange; the Gray permutation is a single
// uniform __shfl pull (dst lane depends only on src lane) + compile-time
// register permutation + uniform half-swap (slot bit3 ^= srcLane bit0).
//
// OUTPUT: out_size==131072 -> float32 real part, row-major (128,1024)
// (verified passing in R4). 262144 fallback = bf16 (re,im) interleaved.

#define DIM 1024
#define NQ 10
#define NLAYERS 8
#define NGATES 80

__device__ __forceinline__ unsigned short f2bf(float f) {
    unsigned int u = __float_as_uint(f);
    unsigned int r = u + 0x7FFFu + ((u >> 16) & 1u);
    return (unsigned short)(r >> 16);
}

// n = c0*x0 + c1*x1 (complex, float2 = re,im)
__device__ __forceinline__ float2 cmadd2(float2 c0, float2 x0, float2 c1, float2 x1) {
    float re = c0.x * x0.x - c0.y * x0.y + c1.x * x1.x - c1.y * x1.y;
    float im = c0.x * x0.y + c0.y * x0.x + c1.x * x1.y + c1.y * x1.x;
    return make_float2(re, im);
}

template <int K>  // amp-bit K in [0,3]: register-local gate
__device__ __forceinline__ void local_gate(float2 (&a)[16], float2 m11, float2 m12,
                                           float2 m21, float2 m22) {
#pragma unroll
    for (int p = 0; p < 8; ++p) {
        const int i0 = ((p >> K) << (K + 1)) | (p & ((1 << K) - 1));
        const int i1 = i0 | (1 << K);
        const float2 a0 = a[i0];
        const float2 a1 = a[i1];
        a[i0] = cmadd2(m11, a0, m12, a1);
        a[i1] = cmadd2(m21, a0, m22, a1);
    }
}

template <int M>  // lane-bit M in [0,5]: cross-lane gate via shfl_xor
__device__ __forceinline__ void cross_gate(float2 (&a)[16], int lane, float2 m11,
                                           float2 m12, float2 m21, float2 m22) {
    const bool hi = (lane >> M) & 1;          // my amp is a1 if set
    const float2 cs = hi ? m22 : m11;         // coeff for my amp
    const float2 co = hi ? m21 : m12;         // coeff for partner amp
#pragma unroll
    for (int r = 0; r < 16; ++r) {
        float2 o;
        o.x = __shfl_xor(a[r].x, 1 << M, 64);
        o.y = __shfl_xor(a[r].y, 1 << M, 64);
        a[r] = cmadd2(cs, a[r], co, o);
    }
}

// state'[x ^ (x>>1)] = state[x], x = (lane<<4)|slot.
__device__ __forceinline__ void gray_permute(float2 (&a)[16], int lane) {
    // src lane S with lane == S ^ (S>>1) (6-bit inverse Gray)
    int S = lane;
    S ^= S >> 1; S ^= S >> 2; S ^= S >> 4;
    S &= 63;
    float2 tmp[16];
#pragma unroll
    for (int r = 0; r < 16; ++r) {
        tmp[r].x = __shfl(a[r].x, S, 64);
        tmp[r].y = __shfl(a[r].y, S, 64);
    }
    // slot map: dst = (t ^ (t>>1)) ^ (S0<<3); do compile-time part first
#pragma unroll
    for (int t = 0; t < 16; ++t) a[t ^ (t >> 1)] = tmp[t];
    const bool s0 = S & 1;
#pragma unroll
    for (int s = 0; s < 8; ++s) {
        const float2 lo = a[s], hi2 = a[s + 8];
        a[s]     = s0 ? hi2 : lo;
        a[s + 8] = s0 ? lo : hi2;
    }
}

__global__ __launch_bounds__(64) void
UnitaryR3Ansatz_18846316495450_kernel(const float* __restrict__ inp,     // [128][1024] f32
                                      const float* __restrict__ params,  // [32][8][10][3] f32
                                      void* __restrict__ outp,
                                      int out_size)
{
    __shared__ float4 gates[NGATES][2];  // [0]=(m11,m12) re/im, [1]=(m21,m22)

    const int b = blockIdx.x;      // vector 0..127
    const int c = b >> 2;          // params copy
    const int lane = threadIdx.x;  // 0..63 (one wave)

    for (int gi = lane; gi < NGATES; gi += 64) {
        const float* p = params + c * (NGATES * 3) + gi * 3;
        const float omega = p[0], theta = p[1], phi = p[2];
        float sh, ch;  sincosf(0.5f * theta, &sh, &ch);
        float sa, ca;  sincosf(0.5f * (phi + omega), &sa, &ca);
        float sb, cb;  sincosf(0.5f * (phi - omega), &sb, &cb);
        gates[gi][0] = make_float4(ca * ch, -sa * ch, -cb * sh, -sb * sh);  // m11, m12
        gates[gi][1] = make_float4(cb * sh, -sb * sh, ca * ch, sa * ch);    // m21, m22
    }

    // ---- load 16 amps per lane: x = b*1024 + lane*16 + i ----
    float2 a[16];
    const float4* xv = (const float4*)(inp + b * DIM + lane * 16);
#pragma unroll
    for (int i = 0; i < 4; ++i) {
        const float4 v = xv[i];
        a[4 * i + 0] = make_float2(v.x, 0.0f);
        a[4 * i + 1] = make_float2(v.y, 0.0f);
        a[4 * i + 2] = make_float2(v.z, 0.0f);
        a[4 * i + 3] = make_float2(v.w, 0.0f);
    }

    __syncthreads();  // single wave: one cheap s_barrier for gate-table visibility

    for (int l = 0; l < NLAYERS; ++l) {
        float2 m11, m12, m21, m22;
#define LOADG(q)                                        \
        {                                               \
            const float4 g0 = gates[l * NQ + (q)][0];   \
            const float4 g1 = gates[l * NQ + (q)][1];   \
            m11 = make_float2(g0.x, g0.y);              \
            m12 = make_float2(g0.z, g0.w);              \
            m21 = make_float2(g1.x, g1.y);              \
            m22 = make_float2(g1.z, g1.w);              \
        }
        // qubit q acts on bit k=9-q; k>=4 => lane bit M=k-4
        LOADG(0); cross_gate<5>(a, lane, m11, m12, m21, m22);
        LOADG(1); cross_gate<4>(a, lane, m11, m12, m21, m22);
        LOADG(2); cross_gate<3>(a, lane, m11, m12, m21, m22);
        LOADG(3); cross_gate<2>(a, lane, m11, m12, m21, m22);
        LOADG(4); cross_gate<1>(a, lane, m11, m12, m21, m22);
        LOADG(5); cross_gate<0>(a, lane, m11, m12, m21, m22);
        LOADG(6); local_gate<3>(a, m11, m12, m21, m22);
        LOADG(7); local_gate<2>(a, m11, m12, m21, m22);
        LOADG(8); local_gate<1>(a, m11, m12, m21, m22);
        LOADG(9); local_gate<0>(a, m11, m12, m21, m22);
#undef LOADG
        gray_permute(a, lane);
    }

    if (out_size >= 2 * DIM * 128) {
        // bf16 (re,im) interleaved fallback
        ushort2* o2 = (ushort2*)outp + (size_t)b * DIM + lane * 16;
#pragma unroll
        for (int i = 0; i < 16; ++i) {
            ushort2 v; v.x = f2bf(a[i].x); v.y = f2bf(a[i].y);
            o2[i] = v;
        }
    } else {
        // float32 real part (the verified layout)
        float4* of = (float4*)((float*)outp + (size_t)b * DIM + lane * 16);
#pragma unroll
        for (int i = 0; i < 4; ++i) {
            of[i] = make_float4(a[4 * i + 0].x, a[4 * i + 1].x,
                                a[4 * i + 2].x, a[4 * i + 3].x);
        }
    }
}

extern "C" void kernel_launch(void* const* d_in, const int* in_sizes, int n_in,
                              void* d_out, int out_size, void* d_ws, size_t ws_size,
                              hipStream_t stream) {
    const float* inp    = (const float*)d_in[0];   // 131072 f32
    const float* params = (const float*)d_in[1];   // 7680 f32
    (void)in_sizes; (void)n_in; (void)d_ws; (void)ws_size;
    UnitaryR3Ansatz_18846316495450_kernel<<<128, 64, 0, stream>>>(inp, params, d_out, out_size);
}

// Round 6
// 68.977 us; speedup vs baseline: 1.3053x; 1.3053x over previous
//
#include <hip/hip_runtime.h>

// Quantum state-vector simulation: out[b] = Re( M[b>>2] @ input[b] ).
// Qubit q <-> amp bit (9-q). Entangler == Gray permute: state'[x^(x>>1)] = state[x].
//
// R6: 128 blocks x 256 threads (4 waves). Lane holds 4 amps (bits 0-1).
// bits 2-7 = lane bits (shfl_xor, latency hidden across 4 waves/CU),
// bits 8-9 = wave bits: handled in ONE double-buffered LDS exchange per layer
// that fuses gates(q1,q0) + the Gray permutation. 9 barriers total.
// OUTPUT: out_size==131072 -> f32 real part (verified R4/R5); 262144 -> bf16 fallback.

#define DIM 1024
#define NQ 10
#define NLAYERS 8
#define NGATES 80

__device__ __forceinline__ unsigned short f2bf(float f) {
    unsigned int u = __float_as_uint(f);
    unsigned int r = u + 0x7FFFu + ((u >> 16) & 1u);
    return (unsigned short)(r >> 16);
}

// c0*x0 + c1*x1, complex
__device__ __forceinline__ float2 cmadd2(float2 c0, float2 x0, float2 c1, float2 x1) {
    float re = c0.x * x0.x - c0.y * x0.y + c1.x * x1.x - c1.y * x1.y;
    float im = c0.x * x0.y + c0.y * x0.x + c1.x * x1.y + c1.y * x1.x;
    return make_float2(re, im);
}

template <int K>  // amp bit K in {0,1}: register-local pairs within a[4]
__device__ __forceinline__ void local_gate(float2 (&a)[4], float2 m11, float2 m12,
                                           float2 m21, float2 m22) {
#pragma unroll
    for (int p = 0; p < 2; ++p) {
        const int i0 = ((p >> K) << (K + 1)) | (p & ((1 << K) - 1));
        const int i1 = i0 | (1 << K);
        const float2 a0 = a[i0], a1 = a[i1];
        a[i0] = cmadd2(m11, a0, m12, a1);
        a[i1] = cmadd2(m21, a0, m22, a1);
    }
}

template <int M>  // lane bit M in [0,5] == amp bit M+2 (verified on HW in R5)
__device__ __forceinline__ void cross_gate(float2 (&a)[4], int lane, float2 m11,
                                           float2 m12, float2 m21, float2 m22) {
    const bool hi = (lane >> M) & 1;
    const float2 cs = hi ? m22 : m11;
    const float2 co = hi ? m21 : m12;
#pragma unroll
    for (int r = 0; r < 4; ++r) {
        float2 o;
        o.x = __shfl_xor(a[r].x, 1 << M, 64);
        o.y = __shfl_xor(a[r].y, 1 << M, 64);
        a[r] = cmadd2(cs, a[r], co, o);
    }
}

__global__ __launch_bounds__(256) void
UnitaryR3Ansatz_18846316495450_kernel(const float* __restrict__ inp,     // [128][1024] f32
                                      const float* __restrict__ params,  // [32][8][10][3] f32
                                      void* __restrict__ outp,
                                      int out_size)
{
    __shared__ float4 gates[NGATES][2];   // [0]=(m11,m12), [1]=(m21,m22) re/im packed
    __shared__ float4 stA[DIM / 2];       // state buffers, float2[1024] viewed as float4
    __shared__ float4 stB[DIM / 2];

    const int b = blockIdx.x;        // vector 0..127
    const int c = b >> 2;            // params copy
    const int tid = threadIdx.x;     // 0..255 == amp bits 2-9
    const int lane = tid & 63;       // amp bits 2-7

    if (tid < NGATES) {
        const float* p = params + c * (NGATES * 3) + tid * 3;
        const float omega = p[0], theta = p[1], phi = p[2];
        float sh, ch;  sincosf(0.5f * theta, &sh, &ch);
        float sa, ca;  sincosf(0.5f * (phi + omega), &sa, &ca);
        float sb, cb;  sincosf(0.5f * (phi - omega), &sb, &cb);
        gates[tid][0] = make_float4(ca * ch, -sa * ch, -cb * sh, -sb * sh);  // m11,m12
        gates[tid][1] = make_float4(cb * sh, -sb * sh, ca * ch, sa * ch);    // m21,m22
    }

    float2 a[4];
    {
        const float4 v = ((const float4*)(inp + b * DIM))[tid];
        a[0] = make_float2(v.x, 0.f);
        a[1] = make_float2(v.y, 0.f);
        a[2] = make_float2(v.z, 0.f);
        a[3] = make_float2(v.w, 0.f);
    }

    // ---- exchange constants: y = my output amp = tid*4 + r; z = invgray10(y) ----
    const int xb = tid << 2;
    int zb = xb;
    zb ^= zb >> 1; zb ^= zb >> 2; zb ^= zb >> 4; zb ^= zb >> 8;  // invgray of (y with r=0)
    const int  zmid = zb & 0xFC;        // z bits 2-7 (constant over r)
    const bool z8 = (zb >> 8) & 1;      // z bit 8 (constant over r)
    const bool z9 = (zb >> 9) & 1;      // z bit 9
    const bool s0 = zb & 1;             // z low-2 offset: zlow2(r) = (zb ^ gray2(r)) & 3
    const bool s1 = zb & 2;

    __syncthreads();

    float4* buf = stA;
    for (int l = 0; l < NLAYERS; ++l) {
        float2 m11, m12, m21, m22;
#define LOADG(q) { const float4 g0 = gates[l * NQ + (q)][0]; \
                   const float4 g1 = gates[l * NQ + (q)][1]; \
                   m11 = make_float2(g0.x, g0.y); m12 = make_float2(g0.z, g0.w); \
                   m21 = make_float2(g1.x, g1.y); m22 = make_float2(g1.z, g1.w); }
        // rotation gates commute (disjoint qubits): apply cheap->expensive
        LOADG(9); local_gate<0>(a, m11, m12, m21, m22);   // qubit 9 -> bit 0
        LOADG(8); local_gate<1>(a, m11, m12, m21, m22);   // qubit 8 -> bit 1
        LOADG(7); cross_gate<0>(a, lane, m11, m12, m21, m22);  // bit 2
        LOADG(6); cross_gate<1>(a, lane, m11, m12, m21, m22);  // bit 3
        LOADG(5); cross_gate<2>(a, lane, m11, m12, m21, m22);  // bit 4
        LOADG(4); cross_gate<3>(a, lane, m11, m12, m21, m22);  // bit 5
        LOADG(3); cross_gate<4>(a, lane, m11, m12, m21, m22);  // bit 6
        LOADG(2); cross_gate<5>(a, lane, m11, m12, m21, m22);  // bit 7

        // ---- LDS exchange: gates on bits 8,9 (qubits 1,0) + Gray permute ----
        buf[tid * 2]     = make_float4(a[0].x, a[0].y, a[1].x, a[1].y);
        buf[tid * 2 + 1] = make_float4(a[2].x, a[2].y, a[3].x, a[3].y);
        __syncthreads();

        LOADG(1);  // qubit 1 -> bit 8; row select by my output z8
        const float2 h0 = z8 ? m21 : m11;
        const float2 h1 = z8 ? m22 : m12;
        LOADG(0);  // qubit 0 -> bit 9; row select by z9
        const float2 g0r = z9 ? m21 : m11;
        const float2 g1r = z9 ? m22 : m12;
#undef LOADG

        // read clusters s[b9][b8][zmid][slot 0..3] and contract over b8 then b9
        float2 v0[4], v1[4];
        {   // b9 = 0
            const float4 p0 = buf[(zmid) >> 1],          p1 = buf[((zmid) >> 1) + 1];
            const float4 q0 = buf[(0x100 | zmid) >> 1],  q1 = buf[((0x100 | zmid) >> 1) + 1];
            v0[0] = cmadd2(h0, make_float2(p0.x, p0.y), h1, make_float2(q0.x, q0.y));
            v0[1] = cmadd2(h0, make_float2(p0.z, p0.w), h1, make_float2(q0.z, q0.w));
            v0[2] = cmadd2(h0, make_float2(p1.x, p1.y), h1, make_float2(q1.x, q1.y));
            v0[3] = cmadd2(h0, make_float2(p1.z, p1.w), h1, make_float2(q1.z, q1.w));
        }
        {   // b9 = 1
            const float4 p0 = buf[(0x200 | zmid) >> 1],  p1 = buf[((0x200 | zmid) >> 1) + 1];
            const float4 q0 = buf[(0x300 | zmid) >> 1],  q1 = buf[((0x300 | zmid) >> 1) + 1];
            v1[0] = cmadd2(h0, make_float2(p0.x, p0.y), h1, make_float2(q0.x, q0.y));
            v1[1] = cmadd2(h0, make_float2(p0.z, p0.w), h1, make_float2(q0.z, q0.w));
            v1[2] = cmadd2(h0, make_float2(p1.x, p1.y), h1, make_float2(q1.x, q1.y));
            v1[3] = cmadd2(h0, make_float2(p1.z, p1.w), h1, make_float2(q1.z, q1.w));
        }
        float2 u[4];
#pragma unroll
        for (int j = 0; j < 4; ++j) u[j] = cmadd2(g0r, v0[j], g1r, v1[j]);

        // a[r] = u[(zb ^ gray2(r)) & 3]: XOR-permute by zb&3, then static gray map
        const float2 w0 = s0 ? u[1] : u[0];
        const float2 w1 = s0 ? u[0] : u[1];
        const float2 w2 = s0 ? u[3] : u[2];
        const float2 w3 = s0 ? u[2] : u[3];
        a[0] = s1 ? w2 : w0;   // u2[0]
        a[1] = s1 ? w3 : w1;   // u2[1]
        a[2] = s1 ? w1 : w3;   // u2[3]  (gray2(2)=3)
        a[3] = s1 ? w0 : w2;   // u2[2]  (gray2(3)=2)

        buf = (l & 1) ? stA : stB;   // double buffer: next layer writes the other one
    }

    if (out_size >= 2 * DIM * 128) {
        // bf16 (re,im) interleaved fallback
        ushort2* o2 = (ushort2*)outp + (size_t)b * DIM + tid * 4;
#pragma unroll
        for (int i = 0; i < 4; ++i) {
            ushort2 v; v.x = f2bf(a[i].x); v.y = f2bf(a[i].y);
            o2[i] = v;
        }
    } else {
        // float32 real part (verified layout)
        ((float4*)((float*)outp + (size_t)b * DIM))[tid] =
            make_float4(a[0].x, a[1].x, a[2].x, a[3].x);
    }
}

extern "C" void kernel_launch(void* const* d_in, const int* in_sizes, int n_in,
                              void* d_out, int out_size, void* d_ws, size_t ws_size,
                              hipStream_t stream) {
    const float* inp    = (const float*)d_in[0];   // 131072 f32
    const float* params = (const float*)d_in[1];   // 7680 f32
    (void)in_sizes; (void)n_in; (void)d_ws; (void)ws_size;
    UnitaryR3Ansatz_18846316495450_kernel<<<128, 256, 0, stream>>>(inp, params, d_out, out_size);
}